// Round 5
// baseline (812.445 us; speedup 1.0000x reference)
//
#include <hip/hip_runtime.h>

#define NNODES 50000
#define NEDGES 640000
#define NF 128
#define EF 128
#define UF 64
#define HID 256
#define ZK 448  // NF + HID + UF
#define NSCANB 196  // ceil(NNODES/256)

typedef float floatx4 __attribute__((ext_vector_type(4)));
typedef __bf16 bf16x8 __attribute__((ext_vector_type(8)));

__device__ __forceinline__ unsigned short f2bf(float f) {
    unsigned int u = __float_as_uint(f);
    u += 0x7fffu + ((u >> 16) & 1u);   // RNE
    return (unsigned short)(u >> 16);
}

__device__ __forceinline__ float bf2f(unsigned short h) {
    return __uint_as_float(((unsigned int)h) << 16);
}

// wt[n*K + k] = w[k*N + n]  (K-major bf16 copy for MFMA B-operand loads)
__global__ void kconv_t(const float* __restrict__ w, unsigned short* __restrict__ wt,
                        int K, int N) {
    int i = blockIdx.x * 256 + threadIdx.x;
    if (i >= K * N) return;
    int n = i / K, k = i - n * K;
    wt[i] = f2bf(w[(size_t)k * N + n]);
}

// x -> bf16 (row-major copy), read ~13x as edge-source gather in kscat
__global__ void kxb(const float* __restrict__ x, unsigned short* __restrict__ xb) {
    int i = blockIdx.x * 256 + threadIdx.x;
    if (i >= NNODES * NF / 4) return;
    float4 v = *(const float4*)(x + (size_t)i * 4);
    unsigned lo = (unsigned)f2bf(v.x) | ((unsigned)f2bf(v.y) << 16);
    unsigned hi = (unsigned)f2bf(v.z) | ((unsigned)f2bf(v.w) << 16);
    *(uint2*)&xb[(size_t)i * 4] = make_uint2(lo, hi);
}

// W3' fold: rows [128,384) of W3 replaced by W23 = W2 @ W3[128:384]; K-major bf16.
__global__ void kfold_w(const float* __restrict__ W2, const float* __restrict__ W3,
                        unsigned short* __restrict__ W3tp) {
    const int k = blockIdx.x;     // 0..447
    const int n = threadIdx.x;    // 0..255
    float v;
    if (k < NF || k >= NF + HID) {
        v = W3[(size_t)k * HID + n];
    } else {
        const int j = k - NF;
        float s = 0.f;
        for (int c = 0; c < HID; ++c)
            s += W2[(size_t)j * HID + c] * W3[(size_t)(NF + c) * HID + n];
        v = s;
    }
    W3tp[(size_t)n * ZK + k] = f2bf(v);
}

// b3' = b3 + b2 @ W3[128:384]
__global__ void kfold_b(const float* __restrict__ b2, const float* __restrict__ b3,
                        const float* __restrict__ W3, float* __restrict__ b3p) {
    const int n = threadIdx.x;
    float s = b3[n];
    for (int c = 0; c < HID; ++c)
        s += b2[c] * W3[(size_t)(NF + c) * HID + n];
    b3p[n] = s;
}

__global__ void kcount(const int* __restrict__ eidx, int* __restrict__ cnt) {
    int i = blockIdx.x * 256 + threadIdx.x;
    if (i < NEDGES) atomicAdd(&cnt[eidx[NEDGES + i]], 1);
}

__global__ void kscan1(const int* __restrict__ cnt, int* __restrict__ excl,
                       int* __restrict__ btot) {
    __shared__ int s[256];
    const int t = threadIdx.x, i = blockIdx.x * 256 + t;
    int v = (i < NNODES) ? cnt[i] : 0;
    s[t] = v;
    __syncthreads();
    for (int off = 1; off < 256; off <<= 1) {
        int add = (t >= off) ? s[t - off] : 0;
        __syncthreads();
        s[t] += add;
        __syncthreads();
    }
    if (i < NNODES) excl[i] = s[t] - v;
    if (t == 255) btot[blockIdx.x] = s[255];
}

__global__ void kscan2(int* __restrict__ btot) {
    __shared__ int s[256];
    const int t = threadIdx.x;
    int v = (t < NSCANB) ? btot[t] : 0;
    s[t] = v;
    __syncthreads();
    for (int off = 1; off < 256; off <<= 1) {
        int add = (t >= off) ? s[t - off] : 0;
        __syncthreads();
        s[t] += add;
        __syncthreads();
    }
    if (t < NSCANB) btot[t] = s[t] - v;
}

__global__ void kstart(const int* __restrict__ cnt, const int* __restrict__ excl,
                       const int* __restrict__ btot, int* __restrict__ head,
                       float* __restrict__ inv) {
    int i = blockIdx.x * 256 + threadIdx.x;
    if (i >= NNODES) return;
    head[i] = excl[i] + btot[blockIdx.x];
    int c = cnt[i];
    inv[i] = 1.0f / (float)(c > 1 ? c : 1);
}

// packed (edge, dest) per sorted position: ONE 8B scattered store instead of
// two 4B (halves dirty-line count of the scatter pass)
__global__ void kscatter(const int* __restrict__ eidx, int* __restrict__ head,
                         uint2* __restrict__ osd) {
    int e = blockIdx.x * 256 + threadIdx.x;
    if (e < NEDGES) {
        int d = eidx[NEDGES + e];
        int p = atomicAdd(&head[d], 1);
        osd[p] = make_uint2((unsigned)e, (unsigned)d);
    }
}

// 256-col bf16 tile stride: 264*2=528 B, 16B-aligned, rows step 4 banks (2-way max)
#define ESE2 264
#define SZ_BYTES (128 * ESE2 * 2)            // 67584
#define SMEM_BYTES (SZ_BYTES + 3 * 128 * 4 + 8)  // + sRow/sCol/sOrd + prev/next

// LDS row rho holds sorted-edge slot sid128(rho) = quad*32 + mi*4 + r
// (rho bits: r=rho&3, quad=(rho>>2)&3, mi=rho>>4). A thread's 32 C-rows
// (8 mi x 4 r at quad*4+r+mi*16) then map to 32 CONSECUTIVE sorted edges
// quad*32..+31. Column order STANDARD: quad's 16 atomic lanes = 16
// consecutive dwords = ONE 64B line (dense-line ops; round-2 proved
// spreading costs 2.4x).
__device__ __forceinline__ int sid128(int r) {
    return (((r >> 2) & 3) << 5) + ((r >> 4) << 2) + (r & 3);
}

// per 128-sorted-edge tile: h1r = relu([xb[row] || ea] @ W1 + b1) (K=256 MFMA),
// 8 waves, each wave = all 128 rows x 32 cols (acc[8][2]).
// Epilogue exploits COLUMN-UNIFORM run structure: nodes fully inside this
// tile are written by no other block -> plain stores; only nodes spanning
// the tile boundary (~2/tile) use atomics. Segment head/tail partials are
// chained across the wave's 4 quads via __shfl with uniform link flags.
__global__ __launch_bounds__(512, 4)
void kscat(const float* __restrict__ ea, const unsigned short* __restrict__ xb,
           const int* __restrict__ eidx, const uint2* __restrict__ osd,
           const unsigned short* __restrict__ W1t,
           const float* __restrict__ b1, float* __restrict__ agg) {
    extern __shared__ char smem[];
    unsigned short* sZ = (unsigned short*)smem;
    int* sRow = (int*)(smem + SZ_BYTES);
    int* sCol = (int*)(smem + SZ_BYTES + 512);
    int* sOrd = (int*)(smem + SZ_BYTES + 1024);
    int* sPN  = (int*)(smem + SZ_BYTES + 1536);  // [0]=prevD, [1]=nextD
    const int tid = threadIdx.x;
    // XCD swizzle: contiguous sorted-edge ranges per XCD -> agg locality in local L2
    const int vb = (blockIdx.x & 7) * 625 + (blockIdx.x >> 3);
    const int e0 = vb * 128;

    if (tid < 128) {
        uint2 od = osd[e0 + tid];
        sOrd[tid] = (int)od.x;
        sCol[tid] = (int)od.y;
        sRow[tid] = eidx[od.x];
        if (tid == 0) sPN[0] = (vb > 0) ? (int)osd[e0 - 1].y : -1;
        if (tid == 1) sPN[1] = (vb < NEDGES / 128 - 1) ? (int)osd[e0 + 128].y : -1;
    }
    __syncthreads();

    // stage xb[row] gather -> cols [0,128): 2048 x 16B chunks, 4 per thread
    #pragma unroll
    for (int i = 0; i < 4; ++i) {
        int c2 = i * 512 + tid;
        int r = c2 >> 4, ch = c2 & 15;
        uint4 v = *(const uint4*)(xb + (size_t)sRow[sid128(r)] * NF + ch * 8);
        *(uint4*)&sZ[r * ESE2 + ch * 8] = v;
    }
    // stage ea gather (f32->bf16) -> cols [128,256): 4096 float4, 8 per thread
    #pragma unroll
    for (int i = 0; i < 8; ++i) {
        int lin = (i << 11) + (tid << 2);
        int r = lin >> 7, c = lin & 127;
        float4 v = *(const float4*)(ea + (size_t)sOrd[sid128(r)] * EF + c);
        unsigned lo = (unsigned)f2bf(v.x) | ((unsigned)f2bf(v.y) << 16);
        unsigned hi = (unsigned)f2bf(v.z) | ((unsigned)f2bf(v.w) << 16);
        *(uint2*)&sZ[r * ESE2 + NF + c] = make_uint2(lo, hi);
    }
    __syncthreads();

    const int lane = tid & 63, wave = tid >> 6;
    const int l16 = lane & 15, quad = lane >> 4;
    const int nbase = wave * 32;
    const floatx4 fz = {0.f, 0.f, 0.f, 0.f};

    floatx4 acc[8][2];
    #pragma unroll
    for (int mi = 0; mi < 8; ++mi) {
        acc[mi][0] = fz;
        acc[mi][1] = fz;
    }

    #pragma unroll
    for (int ks = 0; ks < 8; ++ks) {
        const int k0 = ks * 32 + quad * 8;
        bf16x8 b0 = *(const bf16x8*)&W1t[(size_t)(nbase + l16) * HID + k0];
        bf16x8 b1v = *(const bf16x8*)&W1t[(size_t)(nbase + 16 + l16) * HID + k0];
        #pragma unroll
        for (int mi = 0; mi < 8; ++mi) {
            bf16x8 a = *(const bf16x8*)&sZ[(mi * 16 + l16) * ESE2 + k0];
            acc[mi][0] = __builtin_amdgcn_mfma_f32_16x16x32_bf16(a, b0, acc[mi][0], 0, 0, 0);
            acc[mi][1] = __builtin_amdgcn_mfma_f32_16x16x32_bf16(a, b1v, acc[mi][1], 0, 0, 0);
        }
    }

    // ---- epilogue ----
    const int sbase = quad * 32;
    // uniform per-block segment descriptors (dest sequence is col-independent)
    const int Da0 = sCol[0],   Da1 = sCol[31];
    const int Db0 = sCol[32],  Db1 = sCol[63];
    const int Dc0 = sCol[64],  Dc1 = sCol[95];
    const int Dd0 = sCol[96],  Dd1 = sCol[127];
    const bool sg0 = (Da0 == Da1), sg1 = (Db0 == Db1),
               sg2 = (Dc0 == Dc1), sg3 = (Dd0 == Dd1);
    const bool lk0 = (Da1 == Db0), lk1 = (Db1 == Dc0), lk2 = (Dc1 == Dd0);
    const int prevD = sPN[0], nextD = sPN[1];

    const int n0c = nbase + l16;
    const int n1c = nbase + 16 + l16;
    const float bias0 = b1[n0c];
    const float bias1 = b1[n1c];

    // walk own 32-edge segment: interior runs -> plain store (exclusive to
    // this tile); head/tail partials kept in registers
    float s0 = 0.f, s1 = 0.f, hs0 = 0.f, hs1 = 0.f;
    {
        int d0 = sCol[sbase];
        bool headOpen = true;
        #pragma unroll
        for (int mi = 0; mi < 8; ++mi)
            #pragma unroll
            for (int r = 0; r < 4; ++r) {
                const int p = mi * 4 + r;
                const float h0 = fmaxf(acc[mi][0][r] + bias0, 0.f);
                const float h1 = fmaxf(acc[mi][1][r] + bias1, 0.f);
                const int d = sCol[sbase + p];
                if (d != d0) {   // uniform branch (col-independent)
                    if (headOpen) {
                        hs0 = s0; hs1 = s1; headOpen = false;
                    } else {
                        agg[(size_t)d0 * HID + n0c] = s0;
                        agg[(size_t)d0 * HID + n1c] = s1;
                    }
                    d0 = d; s0 = 0.f; s1 = 0.f;
                }
                s0 += h0; s1 += h1;
            }
    }
    // tail partial = (s0,s1); head partial = (hs0,hs1) (valid iff multi-run)

    // exchange per-segment partials across quads (all lanes participate)
    float tA0 = __shfl(s0, l16, 64),      tA1 = __shfl(s1, l16, 64);
    float tB0 = __shfl(s0, l16 + 16, 64), tB1 = __shfl(s1, l16 + 16, 64);
    float tC0 = __shfl(s0, l16 + 32, 64), tC1 = __shfl(s1, l16 + 32, 64);
    float tD0 = __shfl(s0, l16 + 48, 64), tD1 = __shfl(s1, l16 + 48, 64);
    float hA0 = __shfl(hs0, l16, 64),      hA1 = __shfl(hs1, l16, 64);
    float hB0 = __shfl(hs0, l16 + 16, 64), hB1 = __shfl(hs1, l16 + 16, 64);
    float hC0 = __shfl(hs0, l16 + 32, 64), hC1 = __shfl(hs1, l16 + 32, 64);
    float hD0 = __shfl(hs0, l16 + 48, 64), hD1 = __shfl(hs1, l16 + 48, 64);

    if (quad == 0) {
        // ---- boundary-run merge, fully static, uniform branches ----
        // seg0 head (multi-run only)
        if (!sg0) {
            if (Da0 == prevD) {
                unsafeAtomicAdd(&agg[(size_t)Da0 * HID + n0c], hA0);
                unsafeAtomicAdd(&agg[(size_t)Da0 * HID + n1c], hA1);
            } else {
                agg[(size_t)Da0 * HID + n0c] = hA0;
                agg[(size_t)Da0 * HID + n1c] = hA1;
            }
        }
        // chain from seg0 tail (always a chain start)
        {
            float c0 = tA0, c1 = tA1;
            bool stop = false; int endSeg = 0;
            if (lk0) { if (sg1) { c0 += tB0; c1 += tB1; endSeg = 1; }
                       else     { c0 += hB0; c1 += hB1; stop = true; } }
            if (!stop && endSeg == 1 && lk1) {
                if (sg2) { c0 += tC0; c1 += tC1; endSeg = 2; }
                else     { c0 += hC0; c1 += hC1; stop = true; } }
            if (!stop && endSeg == 2 && lk2) {
                if (sg3) { c0 += tD0; c1 += tD1; endSeg = 3; }
                else     { c0 += hD0; c1 += hD1; stop = true; } }
            const bool lx = sg0 && (Da0 == prevD);
            const bool rx = (!stop && endSeg == 3) && (Dd1 == nextD);
            if (lx || rx) {
                unsafeAtomicAdd(&agg[(size_t)Da1 * HID + n0c], c0);
                unsafeAtomicAdd(&agg[(size_t)Da1 * HID + n1c], c1);
            } else {
                agg[(size_t)Da1 * HID + n0c] = c0;
                agg[(size_t)Da1 * HID + n1c] = c1;
            }
        }
        // seg1
        if (!sg1 || !lk0) {
            if (!sg1 && !lk0) {
                agg[(size_t)Db0 * HID + n0c] = hB0;
                agg[(size_t)Db0 * HID + n1c] = hB1;
            }
            float c0 = tB0, c1 = tB1;
            bool stop = false; int endSeg = 1;
            if (lk1) { if (sg2) { c0 += tC0; c1 += tC1; endSeg = 2; }
                       else     { c0 += hC0; c1 += hC1; stop = true; } }
            if (!stop && endSeg == 2 && lk2) {
                if (sg3) { c0 += tD0; c1 += tD1; endSeg = 3; }
                else     { c0 += hD0; c1 += hD1; stop = true; } }
            const bool rx = (!stop && endSeg == 3) && (Dd1 == nextD);
            if (rx) {
                unsafeAtomicAdd(&agg[(size_t)Db1 * HID + n0c], c0);
                unsafeAtomicAdd(&agg[(size_t)Db1 * HID + n1c], c1);
            } else {
                agg[(size_t)Db1 * HID + n0c] = c0;
                agg[(size_t)Db1 * HID + n1c] = c1;
            }
        }
        // seg2
        if (!sg2 || !lk1) {
            if (!sg2 && !lk1) {
                agg[(size_t)Dc0 * HID + n0c] = hC0;
                agg[(size_t)Dc0 * HID + n1c] = hC1;
            }
            float c0 = tC0, c1 = tC1;
            bool stop = false; int endSeg = 2;
            if (lk2) { if (sg3) { c0 += tD0; c1 += tD1; endSeg = 3; }
                       else     { c0 += hD0; c1 += hD1; stop = true; } }
            const bool rx = (!stop && endSeg == 3) && (Dd1 == nextD);
            if (rx) {
                unsafeAtomicAdd(&agg[(size_t)Dc1 * HID + n0c], c0);
                unsafeAtomicAdd(&agg[(size_t)Dc1 * HID + n1c], c1);
            } else {
                agg[(size_t)Dc1 * HID + n0c] = c0;
                agg[(size_t)Dc1 * HID + n1c] = c1;
            }
        }
        // seg3
        if (!sg3 || !lk2) {
            if (!sg3 && !lk2) {
                agg[(size_t)Dd0 * HID + n0c] = hD0;
                agg[(size_t)Dd0 * HID + n1c] = hD1;
            }
            if (Dd1 == nextD) {
                unsafeAtomicAdd(&agg[(size_t)Dd1 * HID + n0c], tD0);
                unsafeAtomicAdd(&agg[(size_t)Dd1 * HID + n1c], tD1);
            } else {
                agg[(size_t)Dd1 * HID + n0c] = tD0;
                agg[(size_t)Dd1 * HID + n1c] = tD1;
            }
        }
    }
}

// LDS row stride for 448-wide tiles: 456*2=912 B -> 16B-aligned, banks step 4
#define ZST 456

__global__ __launch_bounds__(256)
void knode(const float* __restrict__ x, const float* __restrict__ agg,
           const float* __restrict__ inv, const float* __restrict__ u,
           const int* __restrict__ batch,
           const unsigned short* __restrict__ W3t, const float* __restrict__ b3,
           const unsigned short* __restrict__ W4t, const float* __restrict__ b4,
           float* __restrict__ out) {
    __shared__ unsigned short sZ[64 * ZST];
    const int tid = threadIdx.x;
    const int n0 = blockIdx.x * 64;

    {
        const int r = tid >> 2, q = tid & 3;
        const int nc = min(n0 + r, NNODES - 1);
        const float invv = inv[nc];
        const int bg = batch[nc];
        for (int j = 0; j < 28; ++j) {
            const int c = q * 112 + (j << 2);
            float4 v;
            if (c < NF) {
                v = *(const float4*)(x + (size_t)nc * NF + c);
            } else if (c < NF + HID) {
                v = *(const float4*)(agg + (size_t)nc * HID + (c - NF));
                v.x *= invv; v.y *= invv; v.z *= invv; v.w *= invv;
            } else {
                v = *(const float4*)(u + (size_t)bg * UF + (c - NF - HID));
            }
            unsigned lo = (unsigned)f2bf(v.x) | ((unsigned)f2bf(v.y) << 16);
            unsigned hi = (unsigned)f2bf(v.z) | ((unsigned)f2bf(v.w) << 16);
            *(uint2*)&sZ[r * ZST + c] = make_uint2(lo, hi);
        }
    }
    __syncthreads();

    const int lane = tid & 63, wave = tid >> 6;
    const int l16 = lane & 15, quad = lane >> 4;
    const floatx4 fz = {0.f, 0.f, 0.f, 0.f};

    // layer 1: t = relu(z @ W3' + b3'), K=448
    {
        const int nbase = wave * 64;
        floatx4 acc[4][4];
        #pragma unroll
        for (int mi = 0; mi < 4; ++mi)
            #pragma unroll
            for (int ni = 0; ni < 4; ++ni) acc[mi][ni] = fz;

        #pragma unroll 2
        for (int ks = 0; ks < 14; ++ks) {
            const int k0 = ks * 32 + quad * 8;
            bf16x8 a[4], b[4];
            #pragma unroll
            for (int mi = 0; mi < 4; ++mi)
                a[mi] = *(const bf16x8*)&sZ[(mi * 16 + l16) * ZST + k0];
            #pragma unroll
            for (int ni = 0; ni < 4; ++ni)
                b[ni] = *(const bf16x8*)&W3t[(size_t)(nbase + ni * 16 + l16) * ZK + k0];
            #pragma unroll
            for (int mi = 0; mi < 4; ++mi)
                #pragma unroll
                for (int ni = 0; ni < 4; ++ni)
                    acc[mi][ni] = __builtin_amdgcn_mfma_f32_16x16x32_bf16(a[mi], b[ni], acc[mi][ni], 0, 0, 0);
        }
        __syncthreads();
        #pragma unroll
        for (int ni = 0; ni < 4; ++ni) {
            const int n = nbase + ni * 16 + l16;
            const float bias = b3[n];
            #pragma unroll
            for (int mi = 0; mi < 4; ++mi)
                #pragma unroll
                for (int r = 0; r < 4; ++r) {
                    const int row = mi * 16 + quad * 4 + r;
                    sZ[row * ZST + n] = f2bf(fmaxf(acc[mi][ni][r] + bias, 0.f));
                }
        }
        __syncthreads();
    }

    // layer 2: out = t @ W4 + b4, K=256, N=128
    {
        const int nbase = wave * 32;
        floatx4 acc[4][2];
        #pragma unroll
        for (int mi = 0; mi < 4; ++mi)
            #pragma unroll
            for (int ni = 0; ni < 2; ++ni) acc[mi][ni] = fz;

        #pragma unroll 2
        for (int ks = 0; ks < 8; ++ks) {
            const int k0 = ks * 32 + quad * 8;
            bf16x8 a[4], b[2];
            #pragma unroll
            for (int mi = 0; mi < 4; ++mi)
                a[mi] = *(const bf16x8*)&sZ[(mi * 16 + l16) * ZST + k0];
            #pragma unroll
            for (int ni = 0; ni < 2; ++ni)
                b[ni] = *(const bf16x8*)&W4t[(size_t)(nbase + ni * 16 + l16) * HID + k0];
            #pragma unroll
            for (int mi = 0; mi < 4; ++mi)
                #pragma unroll
                for (int ni = 0; ni < 2; ++ni)
                    acc[mi][ni] = __builtin_amdgcn_mfma_f32_16x16x32_bf16(a[mi], b[ni], acc[mi][ni], 0, 0, 0);
        }
        #pragma unroll
        for (int ni = 0; ni < 2; ++ni) {
            const int feat = nbase + ni * 16 + l16;
            const float bias = b4[feat];
            #pragma unroll
            for (int mi = 0; mi < 4; ++mi)
                #pragma unroll
                for (int r = 0; r < 4; ++r) {
                    const int row = mi * 16 + quad * 4 + r;
                    const int n = n0 + row;
                    if (n < NNODES)
                        out[(size_t)n * NF + feat] = acc[mi][ni][r] + bias;
                }
        }
    }
}

extern "C" void kernel_launch(void* const* d_in, const int* in_sizes, int n_in,
                              void* d_out, int out_size, void* d_ws, size_t ws_size,
                              hipStream_t stream) {
    const float* x   = (const float*)d_in[0];
    const int*   ei  = (const int*)d_in[1];
    const float* ea  = (const float*)d_in[2];
    const float* u   = (const float*)d_in[3];
    const int*   bat = (const int*)d_in[4];
    const float* W1  = (const float*)d_in[5];
    const float* b1  = (const float*)d_in[6];
    const float* W2  = (const float*)d_in[7];
    const float* b2  = (const float*)d_in[8];
    const float* W3  = (const float*)d_in[9];
    const float* b3  = (const float*)d_in[10];
    const float* W4  = (const float*)d_in[11];
    const float* b4  = (const float*)d_in[12];
    float* out = (float*)d_out;

    char* p = (char*)d_ws;
    float* agg = (float*)p;                   p += (size_t)NNODES * HID * 4;
    int* cnt   = (int*)p;                     p += (size_t)NNODES * 4;
    float* inv = (float*)p;                   p += (size_t)NNODES * 4;
    int* excl  = (int*)p;                     p += (size_t)NNODES * 4;
    int* btot  = (int*)p;                     p += 256 * 4;
    int* head  = (int*)p;                     p += (size_t)NNODES * 4;
    uint2* osd = (uint2*)p;                   p += (size_t)NEDGES * 8;
    unsigned short* xb  = (unsigned short*)p; p += (size_t)NNODES * NF * 2;
    unsigned short* W1t = (unsigned short*)p; p += (size_t)HID * HID * 2;
    unsigned short* W3tp= (unsigned short*)p; p += (size_t)ZK * HID * 2;
    unsigned short* W4t = (unsigned short*)p; p += (size_t)HID * NF * 2;
    float* b3p = (float*)p;                   p += (size_t)HID * 4;

    hipMemsetAsync(agg, 0, (size_t)NNODES * HID * 4, stream);
    hipMemsetAsync(cnt, 0, (size_t)NNODES * 4, stream);

    kconv_t<<<(HID * HID + 255) / 256, 256, 0, stream>>>(W1, W1t, HID, HID);
    kconv_t<<<(HID * NF + 255) / 256, 256, 0, stream>>>(W4, W4t, HID, NF);
    kxb<<<(NNODES * NF / 4 + 255) / 256, 256, 0, stream>>>(x, xb);
    kfold_w<<<ZK, 256, 0, stream>>>(W2, W3, W3tp);
    kfold_b<<<1, 256, 0, stream>>>(b2, b3, W3, b3p);

    kcount<<<(NEDGES + 255) / 256, 256, 0, stream>>>(ei, cnt);
    kscan1<<<NSCANB, 256, 0, stream>>>(cnt, excl, btot);
    kscan2<<<1, 256, 0, stream>>>(btot);
    kstart<<<NSCANB, 256, 0, stream>>>(cnt, excl, btot, head, inv);
    kscatter<<<(NEDGES + 255) / 256, 256, 0, stream>>>(ei, head, osd);

    static bool attr_set = false;
    if (!attr_set) {
        hipFuncSetAttribute((const void*)kscat,
                            hipFuncAttributeMaxDynamicSharedMemorySize, SMEM_BYTES);
        attr_set = true;
    }
    kscat<<<NEDGES / 128, 512, SMEM_BYTES, stream>>>(ea, xb, ei, osd, W1t, b1, agg);
    knode<<<(NNODES + 63) / 64, 256, 0, stream>>>(x, agg, inv, u, bat, W3tp, b3p, W4t, b4, out);
}

// Round 8
// 774.578 us; speedup vs baseline: 1.0489x; 1.0489x over previous
//
#include <hip/hip_runtime.h>

#define NNODES 50000
#define NEDGES 640000
#define NF 128
#define EF 128
#define UF 64
#define HID 256
#define ZK 448  // NF + HID + UF
#define NSCANB 196  // ceil(NNODES/256)

typedef float floatx4 __attribute__((ext_vector_type(4)));
typedef __bf16 bf16x8 __attribute__((ext_vector_type(8)));

__device__ __forceinline__ unsigned short f2bf(float f) {
    unsigned int u = __float_as_uint(f);
    u += 0x7fffu + ((u >> 16) & 1u);   // RNE
    return (unsigned short)(u >> 16);
}

// ---- fragment-swizzled weight layout ----
// Ws[((nblk*KB + kc)*16 + l16)*8 + kr] = W[k][n], k = kc*8+kr, n = nblk*16+l16.
// MFMA B-fragment load (lane l16, k-chunk kc = ks*4+quad) is then 16 lanes
// x 16B CONTIGUOUS (256B per quad) instead of 16 distinct 64B lines at
// 512/896B lane stride -> 16x fewer L2 line-requests per load instruction.

// W1 (256x256) -> swizzled, KB=32
__global__ void kconv_w1s(const float* __restrict__ w, unsigned short* __restrict__ ws) {
    int idx = blockIdx.x * 256 + threadIdx.x;
    if (idx >= HID * HID) return;
    int k = idx >> 8, n = idx & 255;
    ws[((((n >> 4) << 5) + (k >> 3)) * 16 + (n & 15)) * 8 + (k & 7)] =
        f2bf(w[(size_t)k * HID + n]);
}

// W4 (256x128) -> swizzled, KB=32
__global__ void kconv_w4s(const float* __restrict__ w, unsigned short* __restrict__ ws) {
    int idx = blockIdx.x * 256 + threadIdx.x;
    if (idx >= HID * NF) return;
    int k = idx >> 7, n = idx & 127;
    ws[((((n >> 4) << 5) + (k >> 3)) * 16 + (n & 15)) * 8 + (k & 7)] =
        f2bf(w[(size_t)k * NF + n]);
}

// x -> bf16 (row-major copy), read ~13x as edge-source gather in kscat
__global__ void kxb(const float* __restrict__ x, unsigned short* __restrict__ xb) {
    int i = blockIdx.x * 256 + threadIdx.x;
    if (i >= NNODES * NF / 4) return;
    float4 v = *(const float4*)(x + (size_t)i * 4);
    unsigned lo = (unsigned)f2bf(v.x) | ((unsigned)f2bf(v.y) << 16);
    unsigned hi = (unsigned)f2bf(v.z) | ((unsigned)f2bf(v.w) << 16);
    *(uint2*)&xb[(size_t)i * 4] = make_uint2(lo, hi);
}

// W3' fold: rows [128,384) of W3 replaced by W23 = W2 @ W3[128:384];
// output fragment-swizzled (448x256), KB=56.
__global__ void kfold_w(const float* __restrict__ W2, const float* __restrict__ W3,
                        unsigned short* __restrict__ W3s) {
    const int k = blockIdx.x;     // 0..447
    const int n = threadIdx.x;    // 0..255
    float v;
    if (k < NF || k >= NF + HID) {
        v = W3[(size_t)k * HID + n];
    } else {
        const int j = k - NF;
        float s = 0.f;
        for (int c = 0; c < HID; ++c)
            s += W2[(size_t)j * HID + c] * W3[(size_t)(NF + c) * HID + n];
        v = s;
    }
    W3s[(((n >> 4) * 56 + (k >> 3)) * 16 + (n & 15)) * 8 + (k & 7)] = f2bf(v);
}

// b3' = b3 + b2 @ W3[128:384]
__global__ void kfold_b(const float* __restrict__ b2, const float* __restrict__ b3,
                        const float* __restrict__ W3, float* __restrict__ b3p) {
    const int n = threadIdx.x;
    float s = b3[n];
    for (int c = 0; c < HID; ++c)
        s += b2[c] * W3[(size_t)(NF + c) * HID + n];
    b3p[n] = s;
}

__global__ void kcount(const int* __restrict__ eidx, int* __restrict__ cnt) {
    int i = blockIdx.x * 256 + threadIdx.x;
    if (i < NEDGES) atomicAdd(&cnt[eidx[NEDGES + i]], 1);
}

__global__ void kscan1(const int* __restrict__ cnt, int* __restrict__ excl,
                       int* __restrict__ btot) {
    __shared__ int s[256];
    const int t = threadIdx.x, i = blockIdx.x * 256 + t;
    int v = (i < NNODES) ? cnt[i] : 0;
    s[t] = v;
    __syncthreads();
    for (int off = 1; off < 256; off <<= 1) {
        int add = (t >= off) ? s[t - off] : 0;
        __syncthreads();
        s[t] += add;
        __syncthreads();
    }
    if (i < NNODES) excl[i] = s[t] - v;
    if (t == 255) btot[blockIdx.x] = s[255];
}

__global__ void kscan2(int* __restrict__ btot) {
    __shared__ int s[256];
    const int t = threadIdx.x;
    int v = (t < NSCANB) ? btot[t] : 0;
    s[t] = v;
    __syncthreads();
    for (int off = 1; off < 256; off <<= 1) {
        int add = (t >= off) ? s[t - off] : 0;
        __syncthreads();
        s[t] += add;
        __syncthreads();
    }
    if (t < NSCANB) btot[t] = s[t] - v;
}

__global__ void kstart(const int* __restrict__ cnt, const int* __restrict__ excl,
                       const int* __restrict__ btot, int* __restrict__ head,
                       float* __restrict__ inv) {
    int i = blockIdx.x * 256 + threadIdx.x;
    if (i >= NNODES) return;
    head[i] = excl[i] + btot[blockIdx.x];
    int c = cnt[i];
    inv[i] = 1.0f / (float)(c > 1 ? c : 1);
}

// packed (edge, dest) per sorted position: ONE 8B scattered store
__global__ void kscatter(const int* __restrict__ eidx, int* __restrict__ head,
                         uint2* __restrict__ osd) {
    int e = blockIdx.x * 256 + threadIdx.x;
    if (e < NEDGES) {
        int d = eidx[NEDGES + e];
        int p = atomicAdd(&head[d], 1);
        osd[p] = make_uint2((unsigned)e, (unsigned)d);
    }
}

// 256-col bf16 tile stride: 264*2=528 B, 16B-aligned, rows step 4 banks
#define ESE2 264
#define SZ_BYTES (128 * ESE2 * 2)            // 67584
#define SMEM_BYTES (SZ_BYTES + 3 * 128 * 4)  // + sRow/sCol/sOrd = 69120

// LDS row rho holds sorted-edge slot sid128(rho) = quad*32 + mi*4 + r.
// A thread's 32 C-rows map to 32 CONSECUTIVE sorted edges -> run merge
// spans 32 edges. Column order STANDARD: quad's 16 atomic lanes = 16
// consecutive dwords = ONE 64B line (dense-line atomics; round-2/5 proved
// both line-spreading and plain stores cost more HBM traffic).
__device__ __forceinline__ int sid128(int r) {
    return (((r >> 2) & 3) << 5) + ((r >> 4) << 2) + (r & 3);
}

// per 128-sorted-edge tile: h1r = relu([xb[row] || ea] @ W1 + b1) (K=256 MFMA),
// 8 waves, each wave = all 128 rows x 32 cols (acc[8][2]);
// merged-run atomic scatter into agg[dest]
__global__ __launch_bounds__(512, 4)
void kscat(const float* __restrict__ ea, const unsigned short* __restrict__ xb,
           const int* __restrict__ eidx, const uint2* __restrict__ osd,
           const unsigned short* __restrict__ W1s,
           const float* __restrict__ b1, float* __restrict__ agg) {
    extern __shared__ char smem[];
    unsigned short* sZ = (unsigned short*)smem;
    int* sRow = (int*)(smem + SZ_BYTES);
    int* sCol = (int*)(smem + SZ_BYTES + 512);
    int* sOrd = (int*)(smem + SZ_BYTES + 1024);
    const int tid = threadIdx.x;
    // XCD swizzle: contiguous sorted-edge ranges per XCD -> agg locality in local L2
    const int vb = (blockIdx.x & 7) * 625 + (blockIdx.x >> 3);
    const int e0 = vb * 128;

    if (tid < 128) {
        uint2 od = osd[e0 + tid];
        sOrd[tid] = (int)od.x;
        sCol[tid] = (int)od.y;
        sRow[tid] = eidx[od.x];
    }
    __syncthreads();

    // stage xb[row] gather -> cols [0,128): 2048 x 16B chunks, 4 per thread
    #pragma unroll
    for (int i = 0; i < 4; ++i) {
        int c2 = i * 512 + tid;
        int r = c2 >> 4, ch = c2 & 15;
        uint4 v = *(const uint4*)(xb + (size_t)sRow[sid128(r)] * NF + ch * 8);
        *(uint4*)&sZ[r * ESE2 + ch * 8] = v;
    }
    // stage ea gather (f32->bf16) -> cols [128,256): 4096 float4, 8 per thread
    #pragma unroll
    for (int i = 0; i < 8; ++i) {
        int lin = (i << 11) + (tid << 2);
        int r = lin >> 7, c = lin & 127;
        float4 v = *(const float4*)(ea + (size_t)sOrd[sid128(r)] * EF + c);
        unsigned lo = (unsigned)f2bf(v.x) | ((unsigned)f2bf(v.y) << 16);
        unsigned hi = (unsigned)f2bf(v.z) | ((unsigned)f2bf(v.w) << 16);
        *(uint2*)&sZ[r * ESE2 + NF + c] = make_uint2(lo, hi);
    }
    __syncthreads();

    const int lane = tid & 63, wave = tid >> 6;
    const int l16 = lane & 15, quad = lane >> 4;
    const int nbase = wave * 32;
    const floatx4 fz = {0.f, 0.f, 0.f, 0.f};

    floatx4 acc[8][2];
    #pragma unroll
    for (int mi = 0; mi < 8; ++mi) {
        acc[mi][0] = fz;
        acc[mi][1] = fz;
    }

    #pragma unroll
    for (int ks = 0; ks < 8; ++ks) {
        const int k0 = ks * 32 + quad * 8;
        const int kc = ks * 4 + quad;
        // swizzled fragment loads: 16 lanes x 16B contiguous per quad
        bf16x8 b0  = *(const bf16x8*)&W1s[((((wave * 2 + 0) << 5) + kc) * 16 + l16) * 8];
        bf16x8 b1v = *(const bf16x8*)&W1s[((((wave * 2 + 1) << 5) + kc) * 16 + l16) * 8];
        #pragma unroll
        for (int mi = 0; mi < 8; ++mi) {
            bf16x8 a = *(const bf16x8*)&sZ[(mi * 16 + l16) * ESE2 + k0];
            acc[mi][0] = __builtin_amdgcn_mfma_f32_16x16x32_bf16(a, b0, acc[mi][0], 0, 0, 0);
            acc[mi][1] = __builtin_amdgcn_mfma_f32_16x16x32_bf16(a, b1v, acc[mi][1], 0, 0, 0);
        }
    }

    // epilogue (round-4 proven): thread owns 32 consecutive sorted edges
    // (quad*32 + mi*4 + r); merge equal-dest runs across all 32, then atomic.
    #pragma unroll
    for (int ni = 0; ni < 2; ++ni) {
        const int n = nbase + ni * 16 + l16;
        const float bias = b1[n];
        const int sbase = quad * 32;
        int d0 = sCol[sbase];
        float s = 0.f;
        #pragma unroll
        for (int mi = 0; mi < 8; ++mi)
            #pragma unroll
            for (int r = 0; r < 4; ++r) {
                const float h = fmaxf(acc[mi][ni][r] + bias, 0.f);
                const int d = sCol[sbase + mi * 4 + r];
                if (d != d0) {
                    unsafeAtomicAdd(&agg[(size_t)d0 * HID + n], s);
                    d0 = d; s = 0.f;
                }
                s += h;
            }
        unsafeAtomicAdd(&agg[(size_t)d0 * HID + n], s);
    }
}

// LDS row stride for 448-wide tiles: 456*2=912 B -> 16B-aligned, banks step 4
#define ZST 456

__global__ __launch_bounds__(256)
void knode(const float* __restrict__ x, const float* __restrict__ agg,
           const float* __restrict__ inv, const float* __restrict__ u,
           const int* __restrict__ batch,
           const unsigned short* __restrict__ W3s, const float* __restrict__ b3,
           const unsigned short* __restrict__ W4s, const float* __restrict__ b4,
           float* __restrict__ out) {
    __shared__ unsigned short sZ[64 * ZST];
    const int tid = threadIdx.x;
    const int n0 = blockIdx.x * 64;

    {
        const int r = tid >> 2, q = tid & 3;
        const int nc = min(n0 + r, NNODES - 1);
        const float invv = inv[nc];
        const int bg = batch[nc];
        for (int j = 0; j < 28; ++j) {
            const int c = q * 112 + (j << 2);
            float4 v;
            if (c < NF) {
                v = *(const float4*)(x + (size_t)nc * NF + c);
            } else if (c < NF + HID) {
                v = *(const float4*)(agg + (size_t)nc * HID + (c - NF));
                v.x *= invv; v.y *= invv; v.z *= invv; v.w *= invv;
            } else {
                v = *(const float4*)(u + (size_t)bg * UF + (c - NF - HID));
            }
            unsigned lo = (unsigned)f2bf(v.x) | ((unsigned)f2bf(v.y) << 16);
            unsigned hi = (unsigned)f2bf(v.z) | ((unsigned)f2bf(v.w) << 16);
            *(uint2*)&sZ[r * ZST + c] = make_uint2(lo, hi);
        }
    }
    __syncthreads();

    const int lane = tid & 63, wave = tid >> 6;
    const int l16 = lane & 15, quad = lane >> 4;
    const floatx4 fz = {0.f, 0.f, 0.f, 0.f};

    // layer 1: t = relu(z @ W3' + b3'), K=448, KB=56
    {
        floatx4 acc[4][4];
        #pragma unroll
        for (int mi = 0; mi < 4; ++mi)
            #pragma unroll
            for (int ni = 0; ni < 4; ++ni) acc[mi][ni] = fz;

        #pragma unroll 2
        for (int ks = 0; ks < 14; ++ks) {
            const int k0 = ks * 32 + quad * 8;
            const int kc = ks * 4 + quad;
            bf16x8 a[4], b[4];
            #pragma unroll
            for (int mi = 0; mi < 4; ++mi)
                a[mi] = *(const bf16x8*)&sZ[(mi * 16 + l16) * ZST + k0];
            #pragma unroll
            for (int ni = 0; ni < 4; ++ni)
                b[ni] = *(const bf16x8*)&W3s[(((wave * 4 + ni) * 56 + kc) * 16 + l16) * 8];
            #pragma unroll
            for (int mi = 0; mi < 4; ++mi)
                #pragma unroll
                for (int ni = 0; ni < 4; ++ni)
                    acc[mi][ni] = __builtin_amdgcn_mfma_f32_16x16x32_bf16(a[mi], b[ni], acc[mi][ni], 0, 0, 0);
        }
        __syncthreads();
        const int nbase = wave * 64;
        #pragma unroll
        for (int ni = 0; ni < 4; ++ni) {
            const int n = nbase + ni * 16 + l16;
            const float bias = b3[n];
            #pragma unroll
            for (int mi = 0; mi < 4; ++mi)
                #pragma unroll
                for (int r = 0; r < 4; ++r) {
                    const int row = mi * 16 + quad * 4 + r;
                    sZ[row * ZST + n] = f2bf(fmaxf(acc[mi][ni][r] + bias, 0.f));
                }
        }
        __syncthreads();
    }

    // layer 2: out = t @ W4 + b4, K=256 (KB=32), N=128
    {
        floatx4 acc[4][2];
        #pragma unroll
        for (int mi = 0; mi < 4; ++mi)
            #pragma unroll
            for (int ni = 0; ni < 2; ++ni) acc[mi][ni] = fz;

        #pragma unroll 2
        for (int ks = 0; ks < 8; ++ks) {
            const int k0 = ks * 32 + quad * 8;
            const int kc = ks * 4 + quad;
            bf16x8 a[4], b[2];
            #pragma unroll
            for (int mi = 0; mi < 4; ++mi)
                a[mi] = *(const bf16x8*)&sZ[(mi * 16 + l16) * ZST + k0];
            #pragma unroll
            for (int ni = 0; ni < 2; ++ni)
                b[ni] = *(const bf16x8*)&W4s[((((wave * 2 + ni) << 5) + kc) * 16 + l16) * 8];
            #pragma unroll
            for (int mi = 0; mi < 4; ++mi)
                #pragma unroll
                for (int ni = 0; ni < 2; ++ni)
                    acc[mi][ni] = __builtin_amdgcn_mfma_f32_16x16x32_bf16(a[mi], b[ni], acc[mi][ni], 0, 0, 0);
        }
        const int nbase = wave * 32;
        #pragma unroll
        for (int ni = 0; ni < 2; ++ni) {
            const int feat = nbase + ni * 16 + l16;
            const float bias = b4[feat];
            #pragma unroll
            for (int mi = 0; mi < 4; ++mi)
                #pragma unroll
                for (int r = 0; r < 4; ++r) {
                    const int row = mi * 16 + quad * 4 + r;
                    const int n = n0 + row;
                    if (n < NNODES)
                        out[(size_t)n * NF + feat] = acc[mi][ni][r] + bias;
                }
        }
    }
}

extern "C" void kernel_launch(void* const* d_in, const int* in_sizes, int n_in,
                              void* d_out, int out_size, void* d_ws, size_t ws_size,
                              hipStream_t stream) {
    const float* x   = (const float*)d_in[0];
    const int*   ei  = (const int*)d_in[1];
    const float* ea  = (const float*)d_in[2];
    const float* u   = (const float*)d_in[3];
    const int*   bat = (const int*)d_in[4];
    const float* W1  = (const float*)d_in[5];
    const float* b1  = (const float*)d_in[6];
    const float* W2  = (const float*)d_in[7];
    const float* b2  = (const float*)d_in[8];
    const float* W3  = (const float*)d_in[9];
    const float* b3  = (const float*)d_in[10];
    const float* W4  = (const float*)d_in[11];
    const float* b4  = (const float*)d_in[12];
    float* out = (float*)d_out;

    char* p = (char*)d_ws;
    float* agg = (float*)p;                   p += (size_t)NNODES * HID * 4;
    int* cnt   = (int*)p;                     p += (size_t)NNODES * 4;
    float* inv = (float*)p;                   p += (size_t)NNODES * 4;
    int* excl  = (int*)p;                     p += (size_t)NNODES * 4;
    int* btot  = (int*)p;                     p += 256 * 4;
    int* head  = (int*)p;                     p += (size_t)NNODES * 4;
    uint2* osd = (uint2*)p;                   p += (size_t)NEDGES * 8;
    unsigned short* xb  = (unsigned short*)p; p += (size_t)NNODES * NF * 2;
    unsigned short* W1s = (unsigned short*)p; p += (size_t)HID * HID * 2;
    unsigned short* W3s = (unsigned short*)p; p += (size_t)ZK * HID * 2;
    unsigned short* W4s = (unsigned short*)p; p += (size_t)HID * NF * 2;
    float* b3p = (float*)p;                   p += (size_t)HID * 4;

    hipMemsetAsync(agg, 0, (size_t)NNODES * HID * 4, stream);
    hipMemsetAsync(cnt, 0, (size_t)NNODES * 4, stream);

    kconv_w1s<<<(HID * HID + 255) / 256, 256, 0, stream>>>(W1, W1s);
    kconv_w4s<<<(HID * NF + 255) / 256, 256, 0, stream>>>(W4, W4s);
    kxb<<<(NNODES * NF / 4 + 255) / 256, 256, 0, stream>>>(x, xb);
    kfold_w<<<ZK, 256, 0, stream>>>(W2, W3, W3s);
    kfold_b<<<1, 256, 0, stream>>>(b2, b3, W3, b3p);

    kcount<<<(NEDGES + 255) / 256, 256, 0, stream>>>(ei, cnt);
    kscan1<<<NSCANB, 256, 0, stream>>>(cnt, excl, btot);
    kscan2<<<1, 256, 0, stream>>>(btot);
    kstart<<<NSCANB, 256, 0, stream>>>(cnt, excl, btot, head, inv);
    kscatter<<<(NEDGES + 255) / 256, 256, 0, stream>>>(ei, head, osd);

    static bool attr_set = false;
    if (!attr_set) {
        hipFuncSetAttribute((const void*)kscat,
                            hipFuncAttributeMaxDynamicSharedMemorySize, SMEM_BYTES);
        attr_set = true;
    }
    kscat<<<NEDGES / 128, 512, SMEM_BYTES, stream>>>(ea, xb, ei, osd, W1s, b1, agg);
    knode<<<(NNODES + 63) / 64, 256, 0, stream>>>(x, agg, inv, u, bat, W3s, b3p, W4s, b4, out);
}